// Round 1
// baseline (258.662 us; speedup 1.0000x reference)
//
#include <hip/hip_runtime.h>

#define PAD 0
#define CONST_NO 10000
#define Bn 8
#define Sn 64
#define Gn 8
#define Fn 200000
#define Rn 200
#define BMAXn 3
#define KF 64
#define KR 32

// ws layout per state (stride 128 ints): [0]=nf, [1]=nr, [2..65]=fidx, [66..97]=ridx
#define WS_STRIDE 128

__device__ __forceinline__ bool isv(int x) { return x > CONST_NO; }

__global__ __launch_bounds__(256) void match_kernel(
    const int* __restrict__ goals, const int* __restrict__ facts,
    const int* __restrict__ heads, int* __restrict__ ws)
{
    const int state = blockIdx.x;          // b*Sn + s
    const int t = threadIdx.x;
    const int lane = t & 63, wv = t >> 6;
    __shared__ int wave_tot[4];

    const int* q = goals + state * (Gn * 3);
    const int qp = q[0], qa0 = q[1], qa1 = q[2];
    const bool active = (qp != PAD);
    const bool v0 = isv(qa0), v1 = isv(qa1);
    int* out = ws + state * WS_STRIDE;

    // ---------------- facts: first <=64 matches in index order ----------------
    int total = 0;
    const int fmax = active ? Fn : 0;
    for (int base = 0; base < fmax && total < KF; base += 1024) {
        const int f0 = base + t * 4;
        unsigned mbits = 0;
        if (f0 + 3 < Fn) {
            const int4* p4 = (const int4*)(facts + 3 * f0);
            int4 a = p4[0], b4 = p4[1], c4 = p4[2];
            int pr0 = a.x,  x10 = a.y,  x20 = a.z;
            int pr1 = a.w,  x11 = b4.x, x21 = b4.y;
            int pr2 = b4.z, x12 = b4.w, x22 = c4.x;
            int pr3 = c4.y, x13 = c4.z, x23 = c4.w;
            if ((pr0 == qp) && (v0 || x10 == qa0) && (v1 || x20 == qa1)) mbits |= 1u;
            if ((pr1 == qp) && (v0 || x11 == qa0) && (v1 || x21 == qa1)) mbits |= 2u;
            if ((pr2 == qp) && (v0 || x12 == qa0) && (v1 || x22 == qa1)) mbits |= 4u;
            if ((pr3 == qp) && (v0 || x13 == qa0) && (v1 || x23 == qa1)) mbits |= 8u;
        } else {
            #pragma unroll
            for (int u = 0; u < 4; ++u) {
                const int f = f0 + u;
                if (f < Fn) {
                    const int p  = facts[3 * f];
                    const int x1 = facts[3 * f + 1];
                    const int x2 = facts[3 * f + 2];
                    if ((p == qp) && (v0 || x1 == qa0) && (v1 || x2 == qa1))
                        mbits |= (1u << u);
                }
            }
        }
        const int cnt = __popc(mbits);

        // ordered block compaction: wave inclusive scan + cross-wave prefix
        int v = cnt;
        #pragma unroll
        for (int off = 1; off < 64; off <<= 1) {
            int n = __shfl_up(v, off, 64);
            if (lane >= off) v += n;
        }
        if (lane == 63) wave_tot[wv] = v;
        __syncthreads();
        int excl = v - cnt;
        #pragma unroll
        for (int w = 0; w < 4; ++w) if (w < wv) excl += wave_tot[w];
        const int ctot = wave_tot[0] + wave_tot[1] + wave_tot[2] + wave_tot[3];

        int pos = total + excl;
        #pragma unroll
        for (int u = 0; u < 4; ++u) {
            if (mbits & (1u << u)) {
                if (pos < KF) out[2 + pos] = f0 + u;
                pos++;
            }
        }
        total += ctot;
        __syncthreads();   // wave_tot reused next iteration
    }
    if (t == 0) out[0] = (total < KF) ? total : KF;

    // ---------------- rules: first <=32 matches in index order ----------------
    int rcnt = 0;
    if (active && t < Rn) {
        const int h0 = heads[3 * t], h1 = heads[3 * t + 1], h2 = heads[3 * t + 2];
        if ((h0 == qp) && (isv(h1) || v0 || qa0 == h1)
                       && (isv(h2) || v1 || qa1 == h2))
            rcnt = 1;
    }
    int v = rcnt;
    #pragma unroll
    for (int off = 1; off < 64; off <<= 1) {
        int n = __shfl_up(v, off, 64);
        if (lane >= off) v += n;
    }
    if (lane == 63) wave_tot[wv] = v;
    __syncthreads();
    int excl = v - rcnt;
    #pragma unroll
    for (int w = 0; w < 4; ++w) if (w < wv) excl += wave_tot[w];
    const int rtot = wave_tot[0] + wave_tot[1] + wave_tot[2] + wave_tot[3];
    if (rcnt && excl < KR) out[66 + excl] = t;
    if (t == 0) out[1] = (rtot < KR) ? rtot : KR;
}

__global__ __launch_bounds__(256) void select_kernel(
    const int* __restrict__ goals, const float* __restrict__ ss,
    const int* __restrict__ facts, const float* __restrict__ fsc,
    const int* __restrict__ heads, const int* __restrict__ bodies,
    const int* __restrict__ rlens, const float* __restrict__ rsc,
    const int* __restrict__ ws, float* __restrict__ outp)
{
    const int b = blockIdx.x, t = threadIdx.x;
    __shared__ int pref[Sn + 1];
    __shared__ int nf_s[Sn];

    if (t < Sn) {
        const int* w = ws + (b * Sn + t) * WS_STRIDE;
        nf_s[t] = w[0];
        pref[t + 1] = w[0] + w[1];
    }
    __syncthreads();
    if (t == 0) {
        pref[0] = 0;
        for (int s = 0; s < Sn; ++s) pref[s + 1] += pref[s];
    }
    __syncthreads();
    const int total = pref[Sn];

    // goals: Sn slots x Gn goal triples
    for (int item = t; item < Sn * Gn; item += 256) {
        const int i = item >> 3, g = item & 7;
        int trip[3] = {PAD, PAD, PAD};
        if (i < total) {
            int lo = 0, hi = Sn - 1;
            while (lo < hi) {
                const int mid = (lo + hi) >> 1;
                if (pref[mid + 1] <= i) lo = mid + 1; else hi = mid;
            }
            const int s = lo, j = i - pref[s];
            const int* w = ws + (b * Sn + s) * WS_STRIDE;
            const int* q = goals + (b * Sn + s) * (Gn * 3);
            const int qa0 = q[1], qa1 = q[2];
            if (j < nf_s[s]) {
                const int fi = w[2 + j];
                const int f1 = facts[3 * fi + 1], f2 = facts[3 * fi + 2];
                if (g >= 1) {
                    #pragma unroll
                    for (int c = 0; c < 3; ++c) {
                        int x = q[g * 3 + c];
                        if (isv(qa0) && x == qa0) x = f1;
                        else if (isv(qa1) && x == qa1) x = f2;
                        trip[c] = x;
                    }
                }
            } else {
                const int ri = w[66 + (j - nf_s[s])];
                const int h1 = heads[3 * ri + 1], h2 = heads[3 * ri + 2];
                const int len = rlens[ri];
                if (g < BMAXn) {
                    if (g < len) {
                        #pragma unroll
                        for (int c = 0; c < 3; ++c) {
                            int x = bodies[(ri * BMAXn + g) * 3 + c];
                            if (isv(h1) && x == h1) x = qa0;
                            if (isv(h2) && x == h2) x = qa1;
                            trip[c] = x;
                        }
                    }
                } else {
                    trip[0] = q[(g - 2) * 3 + 0];
                    trip[1] = q[(g - 2) * 3 + 1];
                    trip[2] = q[(g - 2) * 3 + 2];
                }
            }
        }
        float* o = outp + ((b * Sn + i) * Gn + g) * 3;
        o[0] = (float)trip[0];
        o[1] = (float)trip[1];
        o[2] = (float)trip[2];
    }

    // scores
    if (t < Sn) {
        const int i = t;
        float sc = 0.f;
        if (i < total) {
            int lo = 0, hi = Sn - 1;
            while (lo < hi) {
                const int mid = (lo + hi) >> 1;
                if (pref[mid + 1] <= i) lo = mid + 1; else hi = mid;
            }
            const int s = lo, j = i - pref[s];
            const int* w = ws + (b * Sn + s) * WS_STRIDE;
            const float st = ss[b * Sn + s];
            if (j < nf_s[s]) sc = st * fsc[w[2 + j]];
            else             sc = st * rsc[w[66 + (j - nf_s[s])]];
        }
        outp[Bn * Sn * Gn * 3 + b * Sn + t] = sc;
    }
}

extern "C" void kernel_launch(void* const* d_in, const int* in_sizes, int n_in,
                              void* d_out, int out_size, void* d_ws, size_t ws_size,
                              hipStream_t stream) {
    const int*   goals  = (const int*)  d_in[0];
    const float* ss     = (const float*)d_in[1];
    const int*   facts  = (const int*)  d_in[2];
    const float* fsc    = (const float*)d_in[3];
    const int*   heads  = (const int*)  d_in[4];
    const int*   bodies = (const int*)  d_in[5];
    const int*   rlens  = (const int*)  d_in[6];
    const float* rsc    = (const float*)d_in[7];
    int*   ws   = (int*)d_ws;
    float* outp = (float*)d_out;

    match_kernel<<<Bn * Sn, 256, 0, stream>>>(goals, facts, heads, ws);
    select_kernel<<<Bn, 256, 0, stream>>>(goals, ss, facts, fsc, heads, bodies,
                                          rlens, rsc, ws, outp);
}

// Round 2
// 114.682 us; speedup vs baseline: 2.2555x; 2.2555x over previous
//
#include <hip/hip_runtime.h>

#define PAD 0
#define CONST_NO 10000
#define Bn 8
#define Sn 64
#define Gn 8
#define Fn 200000
#define Rn 200
#define BMAXn 3
#define KF 64
#define KR 32

// ---- workspace layout (in ints) ----
// per-state results: [0]=nf [1]=nr [2..65]=fidx [66..97]=ridx, stride 128
#define WS_STRIDE   128
#define OFF_RES     0
#define OFF_STARTS  (Bn * Sn * WS_STRIDE)          // 65536, 64 ints
#define OFF_COUNTS  (OFF_STARTS + 64)              // 64 ints
#define NCH         ((Fn + 63) / 64)               // 3125 chunks of 64 facts
#define OFF_HIST    (OFF_COUNTS + 64)              // NCH*64 ints
#define OFF_SIDX    (OFF_HIST + NCH * 64)          // Fn ints
#define OFF_SARGS   (OFF_SIDX + Fn)                // Fn int2 (byte off divisible by 8)

__device__ __forceinline__ bool isv(int x) { return x > CONST_NO; }

// ---------- stable counting-sort of facts by predicate ----------

// per-chunk (64 facts) histogram over predicates 0..63
__global__ __launch_bounds__(256) void hist_kernel(
    const int* __restrict__ facts, int* __restrict__ ws)
{
    __shared__ int h[256];
    const int t = threadIdx.x, lane = t & 63, wv = t >> 6;
    const int c = blockIdx.x * 4 + wv;
    h[t] = 0;
    __syncthreads();
    const int i = c * 64 + lane;
    if (i < Fn) {
        const int p = facts[3 * i];
        atomicAdd(&h[wv * 64 + p], 1);
    }
    __syncthreads();
    if (c < NCH) ws[OFF_HIST + c * 64 + lane] = h[wv * 64 + lane];
}

// per predicate: turn chunk histograms into exclusive cross-chunk offsets;
// write counts[p]. One 64-thread block per predicate (p = 1..50).
__global__ __launch_bounds__(64) void scan_pred_kernel(int* __restrict__ ws)
{
    const int p = blockIdx.x + 1;
    const int lane = threadIdx.x;
    const int CPL = (NCH + 63) / 64;               // chunks per lane
    const int c0 = lane * CPL, c1 = min(NCH, c0 + CPL);
    int* hist = ws + OFF_HIST;

    int sum = 0;
    for (int c = c0; c < c1; ++c) sum += hist[c * 64 + p];
    int incl = sum;
    #pragma unroll
    for (int off = 1; off < 64; off <<= 1) {
        int n = __shfl_up(incl, off, 64);
        if (lane >= off) incl += n;
    }
    if (lane == 63) ws[OFF_COUNTS + p] = incl;
    int run = incl - sum;                          // exclusive prefix
    for (int c = c0; c < c1; ++c) {
        const int tmp = hist[c * 64 + p];
        hist[c * 64 + p] = run;
        run += tmp;
    }
}

// exclusive scan over predicate counts -> starts
__global__ __launch_bounds__(64) void scan_starts_kernel(int* __restrict__ ws)
{
    const int lane = threadIdx.x;
    const int v = (lane >= 1 && lane <= 50) ? ws[OFF_COUNTS + lane] : 0;
    int incl = v;
    #pragma unroll
    for (int off = 1; off < 64; off <<= 1) {
        int n = __shfl_up(incl, off, 64);
        if (lane >= off) incl += n;
    }
    ws[OFF_STARTS + lane] = incl - v;
    if (lane >= 51) ws[OFF_COUNTS + lane] = 0;
    if (lane == 0)  ws[OFF_COUNTS] = 0;
}

// stable scatter: dest = starts[p] + cross-chunk offset + intra-chunk rank
__global__ __launch_bounds__(256) void scatter_kernel(
    const int* __restrict__ facts, int* __restrict__ ws)
{
    __shared__ int pr[256];
    const int t = threadIdx.x, lane = t & 63, wv = t >> 6;
    const int c = blockIdx.x * 4 + wv;
    const int i = c * 64 + lane;
    int p = -1, a0 = 0, a1 = 0;
    if (i < Fn) {
        p  = facts[3 * i];
        a0 = facts[3 * i + 1];
        a1 = facts[3 * i + 2];
    }
    pr[t] = p;
    __syncthreads();
    if (i < Fn) {
        int rank = 0;
        for (int j = 0; j < lane; ++j) rank += (pr[wv * 64 + j] == p);
        const int dest = ws[OFF_STARTS + p] + ws[OFF_HIST + c * 64 + p] + rank;
        ws[OFF_SIDX + dest] = i;
        ((int2*)(ws + OFF_SARGS))[dest] = make_int2(a0, a1);
    }
}

// ---------- match: scan only the query predicate's slice ----------

__global__ __launch_bounds__(256) void match_kernel(
    const int* __restrict__ goals, const int* __restrict__ heads,
    int* __restrict__ ws)
{
    const int state = blockIdx.x;
    const int t = threadIdx.x;
    const int lane = t & 63, wv = t >> 6;
    __shared__ int wave_tot[4];

    const int* q = goals + state * (Gn * 3);
    const int qp = q[0], qa0 = q[1], qa1 = q[2];
    const bool active = (qp != PAD);
    const bool v0 = isv(qa0), v1 = isv(qa1);
    int* out = ws + OFF_RES + state * WS_STRIDE;

    const int st  = active ? ws[OFF_STARTS + qp] : 0;
    const int cnt = active ? ws[OFF_COUNTS + qp] : 0;
    const int2* sargs = (const int2*)(ws + OFF_SARGS);
    const int*  sidx  = ws + OFF_SIDX;

    int total = 0;
    for (int base = 0; base < cnt && total < KF; base += 512) {
        const int k0 = base + t * 2;
        unsigned mbits = 0;
        if (k0 < cnt) {
            const int2 f = sargs[st + k0];
            if ((v0 || f.x == qa0) && (v1 || f.y == qa1)) mbits |= 1u;
        }
        if (k0 + 1 < cnt) {
            const int2 f = sargs[st + k0 + 1];
            if ((v0 || f.x == qa0) && (v1 || f.y == qa1)) mbits |= 2u;
        }
        const int c2 = __popc(mbits);

        int v = c2;
        #pragma unroll
        for (int off = 1; off < 64; off <<= 1) {
            int n = __shfl_up(v, off, 64);
            if (lane >= off) v += n;
        }
        if (lane == 63) wave_tot[wv] = v;
        __syncthreads();
        int excl = v - c2;
        #pragma unroll
        for (int w = 0; w < 4; ++w) if (w < wv) excl += wave_tot[w];
        const int ctot = wave_tot[0] + wave_tot[1] + wave_tot[2] + wave_tot[3];

        int pos = total + excl;
        #pragma unroll
        for (int u = 0; u < 2; ++u) {
            if (mbits & (1u << u)) {
                if (pos < KF) out[2 + pos] = sidx[st + k0 + u];
                pos++;
            }
        }
        total += ctot;
        __syncthreads();
    }
    if (t == 0) out[0] = (total < KF) ? total : KF;

    // rules: first <=32 matches in index order
    int rcnt = 0;
    if (active && t < Rn) {
        const int h0 = heads[3 * t], h1 = heads[3 * t + 1], h2 = heads[3 * t + 2];
        if ((h0 == qp) && (isv(h1) || v0 || qa0 == h1)
                       && (isv(h2) || v1 || qa1 == h2))
            rcnt = 1;
    }
    int v = rcnt;
    #pragma unroll
    for (int off = 1; off < 64; off <<= 1) {
        int n = __shfl_up(v, off, 64);
        if (lane >= off) v += n;
    }
    if (lane == 63) wave_tot[wv] = v;
    __syncthreads();
    int excl = v - rcnt;
    #pragma unroll
    for (int w = 0; w < 4; ++w) if (w < wv) excl += wave_tot[w];
    const int rtot = wave_tot[0] + wave_tot[1] + wave_tot[2] + wave_tot[3];
    if (rcnt && excl < KR) out[66 + excl] = t;
    if (t == 0) out[1] = (rtot < KR) ? rtot : KR;
}

// ---------- select: stable global top-S and goal construction ----------

__global__ __launch_bounds__(256) void select_kernel(
    const int* __restrict__ goals, const float* __restrict__ ss,
    const int* __restrict__ facts, const float* __restrict__ fsc,
    const int* __restrict__ heads, const int* __restrict__ bodies,
    const int* __restrict__ rlens, const float* __restrict__ rsc,
    const int* __restrict__ ws, float* __restrict__ outp)
{
    const int b = blockIdx.x, t = threadIdx.x;
    __shared__ int pref[Sn + 1];
    __shared__ int nf_s[Sn];

    if (t < Sn) {
        const int* w = ws + OFF_RES + (b * Sn + t) * WS_STRIDE;
        nf_s[t] = w[0];
        pref[t + 1] = w[0] + w[1];
    }
    __syncthreads();
    if (t == 0) {
        pref[0] = 0;
        for (int s = 0; s < Sn; ++s) pref[s + 1] += pref[s];
    }
    __syncthreads();
    const int total = pref[Sn];

    for (int item = t; item < Sn * Gn; item += 256) {
        const int i = item >> 3, g = item & 7;
        int trip[3] = {PAD, PAD, PAD};
        if (i < total) {
            int lo = 0, hi = Sn - 1;
            while (lo < hi) {
                const int mid = (lo + hi) >> 1;
                if (pref[mid + 1] <= i) lo = mid + 1; else hi = mid;
            }
            const int s = lo, j = i - pref[s];
            const int* w = ws + OFF_RES + (b * Sn + s) * WS_STRIDE;
            const int* q = goals + (b * Sn + s) * (Gn * 3);
            const int qa0 = q[1], qa1 = q[2];
            if (j < nf_s[s]) {
                const int fi = w[2 + j];
                const int f1 = facts[3 * fi + 1], f2 = facts[3 * fi + 2];
                if (g >= 1) {
                    #pragma unroll
                    for (int c = 0; c < 3; ++c) {
                        int x = q[g * 3 + c];
                        if (isv(qa0) && x == qa0) x = f1;
                        else if (isv(qa1) && x == qa1) x = f2;
                        trip[c] = x;
                    }
                }
            } else {
                const int ri = w[66 + (j - nf_s[s])];
                const int h1 = heads[3 * ri + 1], h2 = heads[3 * ri + 2];
                const int len = rlens[ri];
                if (g < BMAXn) {
                    if (g < len) {
                        #pragma unroll
                        for (int c = 0; c < 3; ++c) {
                            int x = bodies[(ri * BMAXn + g) * 3 + c];
                            if (isv(h1) && x == h1) x = qa0;
                            if (isv(h2) && x == h2) x = qa1;
                            trip[c] = x;
                        }
                    }
                } else {
                    trip[0] = q[(g - 2) * 3 + 0];
                    trip[1] = q[(g - 2) * 3 + 1];
                    trip[2] = q[(g - 2) * 3 + 2];
                }
            }
        }
        float* o = outp + ((b * Sn + i) * Gn + g) * 3;
        o[0] = (float)trip[0];
        o[1] = (float)trip[1];
        o[2] = (float)trip[2];
    }

    if (t < Sn) {
        const int i = t;
        float sc = 0.f;
        if (i < total) {
            int lo = 0, hi = Sn - 1;
            while (lo < hi) {
                const int mid = (lo + hi) >> 1;
                if (pref[mid + 1] <= i) lo = mid + 1; else hi = mid;
            }
            const int s = lo, j = i - pref[s];
            const int* w = ws + OFF_RES + (b * Sn + s) * WS_STRIDE;
            const float stt = ss[b * Sn + s];
            if (j < nf_s[s]) sc = stt * fsc[w[2 + j]];
            else             sc = stt * rsc[w[66 + (j - nf_s[s])]];
        }
        outp[Bn * Sn * Gn * 3 + b * Sn + t] = sc;
    }
}

extern "C" void kernel_launch(void* const* d_in, const int* in_sizes, int n_in,
                              void* d_out, int out_size, void* d_ws, size_t ws_size,
                              hipStream_t stream) {
    const int*   goals  = (const int*)  d_in[0];
    const float* ss     = (const float*)d_in[1];
    const int*   facts  = (const int*)  d_in[2];
    const float* fsc    = (const float*)d_in[3];
    const int*   heads  = (const int*)  d_in[4];
    const int*   bodies = (const int*)  d_in[5];
    const int*   rlens  = (const int*)  d_in[6];
    const float* rsc    = (const float*)d_in[7];
    int*   ws   = (int*)d_ws;
    float* outp = (float*)d_out;

    const int nchb = (NCH + 3) / 4;                // 4 chunks (waves) per block
    hist_kernel<<<nchb, 256, 0, stream>>>(facts, ws);
    scan_pred_kernel<<<50, 64, 0, stream>>>(ws);
    scan_starts_kernel<<<1, 64, 0, stream>>>(ws);
    scatter_kernel<<<nchb, 256, 0, stream>>>(facts, ws);
    match_kernel<<<Bn * Sn, 256, 0, stream>>>(goals, heads, ws);
    select_kernel<<<Bn, 256, 0, stream>>>(goals, ss, facts, fsc, heads, bodies,
                                          rlens, rsc, ws, outp);
}

// Round 3
// 102.965 us; speedup vs baseline: 2.5121x; 1.1138x over previous
//
#include <hip/hip_runtime.h>

#define PAD 0
#define CONST_NO 10000
#define Bn 8
#define Sn 64
#define Gn 8
#define Fn 200000
#define Rn 200
#define BMAXn 3
#define KF 64
#define KR 32

// sort geometry: 196 blocks x 1024 facts
#define NBLK 196
#define CHB  1024

// ---- workspace layout (ints) ----
#define WS_STRIDE   128
#define OFF_RES     0                               // 512*128 = 65536
#define OFF_STARTS  (Bn * Sn * WS_STRIDE)           // 64
#define OFF_COUNTS  (OFF_STARTS + 64)               // 64
#define OFF_BHIST   (OFF_COUNTS + 64)               // NBLK*64 = 12544
#define OFF_SORT    78336                           // int4 per fact; 78336*4 % 16 == 0

__device__ __forceinline__ bool isv(int x) { return x > CONST_NO; }

// ---------- 1) per-block predicate histogram ----------
__global__ __launch_bounds__(256) void hist_kernel(
    const int* __restrict__ facts, int* __restrict__ ws)
{
    __shared__ int h[64];
    const int t = threadIdx.x;
    if (t < 64) h[t] = 0;
    __syncthreads();
    const int f0 = blockIdx.x * CHB + t * 4;
    if (f0 + 3 < Fn) {
        const int4* p4 = (const int4*)(facts + 3 * f0);
        int4 a = p4[0], b4 = p4[1], c4 = p4[2];
        atomicAdd(&h[a.x],  1);
        atomicAdd(&h[a.w],  1);
        atomicAdd(&h[b4.z], 1);
        atomicAdd(&h[c4.y], 1);
    } else {
        #pragma unroll
        for (int u = 0; u < 4; ++u)
            if (f0 + u < Fn) atomicAdd(&h[facts[3 * (f0 + u)]], 1);
    }
    __syncthreads();
    if (t < 64) ws[OFF_BHIST + blockIdx.x * 64 + t] = h[t];
}

// ---------- 2) cross-block scan -> absolute dest bases; starts/counts ----------
__global__ __launch_bounds__(256) void scan_kernel(int* __restrict__ ws)
{
    __shared__ int part[4][64];
    __shared__ int qb[4][64];
    const int t = threadIdx.x;
    const int p = t & 63, q = t >> 6;
    const int b0 = q * 49, b1 = b0 + 49;

    int s = 0;
    for (int b = b0; b < b1; ++b) s += ws[OFF_BHIST + b * 64 + p];
    part[q][p] = s;
    __syncthreads();
    if (t < 64) {
        const int t0 = part[0][t], t1 = part[1][t], t2 = part[2][t], t3 = part[3][t];
        const int tot = t0 + t1 + t2 + t3;
        int incl = tot;
        #pragma unroll
        for (int off = 1; off < 64; off <<= 1) {
            int n = __shfl_up(incl, off, 64);
            if (t >= off) incl += n;
        }
        const int start = incl - tot;
        ws[OFF_STARTS + t] = start;
        ws[OFF_COUNTS + t] = tot;
        qb[0][t] = start;
        qb[1][t] = start + t0;
        qb[2][t] = start + t0 + t1;
        qb[3][t] = start + t0 + t1 + t2;
    }
    __syncthreads();
    int run = qb[q][p];
    for (int b = b0; b < b1; ++b) {
        const int v = ws[OFF_BHIST + b * 64 + p];
        ws[OFF_BHIST + b * 64 + p] = run;     // absolute dest base for (block, pred)
        run += v;
    }
}

// ---------- 3) stable scatter into sorted int4 {a0, a1, idx, 0} ----------
__global__ __launch_bounds__(256) void scatter_kernel(
    const int* __restrict__ facts, int* __restrict__ ws)
{
    __shared__ int predAll[CHB];
    __shared__ int coff[16][64];
    const int t = threadIdx.x;

    for (int k = t; k < 16 * 64; k += 256) ((int*)coff)[k] = 0;

    const int f0 = blockIdx.x * CHB + t * 4;
    int pv[4], a0v[4], a1v[4];
    int nvalid = 0;
    if (f0 + 3 < Fn) {
        const int4* p4 = (const int4*)(facts + 3 * f0);
        int4 a = p4[0], b4 = p4[1], c4 = p4[2];
        pv[0] = a.x;  a0v[0] = a.y;  a1v[0] = a.z;
        pv[1] = a.w;  a0v[1] = b4.x; a1v[1] = b4.y;
        pv[2] = b4.z; a0v[2] = b4.w; a1v[2] = c4.x;
        pv[3] = c4.y; a0v[3] = c4.z; a1v[3] = c4.w;
        nvalid = 4;
    } else {
        #pragma unroll
        for (int u = 0; u < 4; ++u) {
            pv[u] = -1; a0v[u] = 0; a1v[u] = 0;
            if (f0 + u < Fn) {
                pv[u]  = facts[3 * (f0 + u)];
                a0v[u] = facts[3 * (f0 + u) + 1];
                a1v[u] = facts[3 * (f0 + u) + 2];
                nvalid = u + 1;
            }
        }
    }
    const int c = t >> 4;                      // chunk of 64 facts within block
    #pragma unroll
    for (int u = 0; u < 4; ++u) {
        predAll[t * 4 + u] = pv[u];
        if (u < nvalid) atomicAdd(&coff[c][pv[u]], 1);
    }
    __syncthreads();
    if (t < 64) {
        int run = ws[OFF_BHIST + blockIdx.x * 64 + t];
        #pragma unroll
        for (int cc = 0; cc < 16; ++cc) {
            const int v = coff[cc][t];
            coff[cc][t] = run;
            run += v;
        }
    }
    __syncthreads();
    int4* sorted = (int4*)(ws + OFF_SORT);
    const int posb = (t & 15) * 4;
    #pragma unroll
    for (int u = 0; u < 4; ++u) {
        if (u < nvalid) {
            const int p = pv[u];
            int rank = 0;
            for (int j = 0; j < posb + u; ++j)
                rank += (predAll[c * 64 + j] == p);
            sorted[coff[c][p] + rank] = make_int4(a0v[u], a1v[u], f0 + u, 0);
        }
    }
}

// ---------- 4) match: scan only the query predicate's slice ----------
__global__ __launch_bounds__(256) void match_kernel(
    const int* __restrict__ goals, const int* __restrict__ heads,
    int* __restrict__ ws)
{
    const int state = blockIdx.x;
    const int t = threadIdx.x;
    const int lane = t & 63, wv = t >> 6;
    __shared__ int wave_tot[4];

    const int* q = goals + state * (Gn * 3);
    const int qp = q[0], qa0 = q[1], qa1 = q[2];
    const bool active = (qp != PAD);
    const bool v0 = isv(qa0), v1 = isv(qa1);
    int* out = ws + OFF_RES + state * WS_STRIDE;

    const int st  = active ? ws[OFF_STARTS + qp] : 0;
    const int cnt = active ? ws[OFF_COUNTS + qp] : 0;
    const int4* S = (const int4*)(ws + OFF_SORT);

    if (v0 && v1) {
        // every fact in the slice matches; first min(cnt,KF) in sorted order
        const int n = (cnt < KF) ? cnt : KF;
        if (t < n) out[2 + t] = S[st + t].z;
        if (t == 0) out[0] = n;
    } else {
        int total = 0;
        for (int base = 0; base < cnt && total < KF; base += 512) {
            const int k0 = base + t * 2;
            unsigned mbits = 0;
            int i0 = 0, i1 = 0;
            if (k0 < cnt) {
                const int4 f = S[st + k0];
                i0 = f.z;
                if ((v0 || f.x == qa0) && (v1 || f.y == qa1)) mbits |= 1u;
            }
            if (k0 + 1 < cnt) {
                const int4 f = S[st + k0 + 1];
                i1 = f.z;
                if ((v0 || f.x == qa0) && (v1 || f.y == qa1)) mbits |= 2u;
            }
            const int c2 = __popc(mbits);

            int v = c2;
            #pragma unroll
            for (int off = 1; off < 64; off <<= 1) {
                int n = __shfl_up(v, off, 64);
                if (lane >= off) v += n;
            }
            if (lane == 63) wave_tot[wv] = v;
            __syncthreads();
            int excl = v - c2;
            #pragma unroll
            for (int w = 0; w < 4; ++w) if (w < wv) excl += wave_tot[w];
            const int ctot = wave_tot[0] + wave_tot[1] + wave_tot[2] + wave_tot[3];

            int pos = total + excl;
            if (mbits & 1u) { if (pos < KF) out[2 + pos] = i0; pos++; }
            if (mbits & 2u) { if (pos < KF) out[2 + pos] = i1; }
            total += ctot;
            __syncthreads();
        }
        if (t == 0) out[0] = (total < KF) ? total : KF;
    }

    // rules: first <=32 matches in index order
    int rcnt = 0;
    if (active && t < Rn) {
        const int h0 = heads[3 * t], h1 = heads[3 * t + 1], h2 = heads[3 * t + 2];
        if ((h0 == qp) && (isv(h1) || v0 || qa0 == h1)
                       && (isv(h2) || v1 || qa1 == h2))
            rcnt = 1;
    }
    __syncthreads();
    int v = rcnt;
    #pragma unroll
    for (int off = 1; off < 64; off <<= 1) {
        int n = __shfl_up(v, off, 64);
        if (lane >= off) v += n;
    }
    if (lane == 63) wave_tot[wv] = v;
    __syncthreads();
    int excl = v - rcnt;
    #pragma unroll
    for (int w = 0; w < 4; ++w) if (w < wv) excl += wave_tot[w];
    const int rtot = wave_tot[0] + wave_tot[1] + wave_tot[2] + wave_tot[3];
    if (rcnt && excl < KR) out[66 + excl] = t;
    if (t == 0) out[1] = (rtot < KR) ? rtot : KR;
}

// ---------- 5) select: stable global top-S + goal construction ----------
__global__ __launch_bounds__(256) void select_kernel(
    const int* __restrict__ goals, const float* __restrict__ ss,
    const int* __restrict__ facts, const float* __restrict__ fsc,
    const int* __restrict__ heads, const int* __restrict__ bodies,
    const int* __restrict__ rlens, const float* __restrict__ rsc,
    const int* __restrict__ ws, float* __restrict__ outp)
{
    const int b = blockIdx.x, t = threadIdx.x;
    __shared__ int pref[Sn + 1];
    __shared__ int nf_s[Sn];

    if (t < Sn) {
        const int* w = ws + OFF_RES + (b * Sn + t) * WS_STRIDE;
        const int nf = w[0];
        nf_s[t] = nf;
        int val = nf + w[1];
        int incl = val;
        #pragma unroll
        for (int off = 1; off < 64; off <<= 1) {
            int n = __shfl_up(incl, off, 64);
            if (t >= off) incl += n;
        }
        pref[t + 1] = incl;
        if (t == 0) pref[0] = 0;
    }
    __syncthreads();
    const int total = pref[Sn];

    for (int item = t; item < Sn * Gn; item += 256) {
        const int i = item >> 3, g = item & 7;
        int trip[3] = {PAD, PAD, PAD};
        if (i < total) {
            int lo = 0, hi = Sn - 1;
            while (lo < hi) {
                const int mid = (lo + hi) >> 1;
                if (pref[mid + 1] <= i) lo = mid + 1; else hi = mid;
            }
            const int s = lo, j = i - pref[s];
            const int* w = ws + OFF_RES + (b * Sn + s) * WS_STRIDE;
            const int* q = goals + (b * Sn + s) * (Gn * 3);
            const int qa0 = q[1], qa1 = q[2];
            if (j < nf_s[s]) {
                const int fi = w[2 + j];
                const int f1 = facts[3 * fi + 1], f2 = facts[3 * fi + 2];
                if (g >= 1) {
                    #pragma unroll
                    for (int c = 0; c < 3; ++c) {
                        int x = q[g * 3 + c];
                        if (isv(qa0) && x == qa0) x = f1;
                        else if (isv(qa1) && x == qa1) x = f2;
                        trip[c] = x;
                    }
                }
            } else {
                const int ri = w[66 + (j - nf_s[s])];
                const int h1 = heads[3 * ri + 1], h2 = heads[3 * ri + 2];
                const int len = rlens[ri];
                if (g < BMAXn) {
                    if (g < len) {
                        #pragma unroll
                        for (int c = 0; c < 3; ++c) {
                            int x = bodies[(ri * BMAXn + g) * 3 + c];
                            if (isv(h1) && x == h1) x = qa0;
                            if (isv(h2) && x == h2) x = qa1;
                            trip[c] = x;
                        }
                    }
                } else {
                    trip[0] = q[(g - 2) * 3 + 0];
                    trip[1] = q[(g - 2) * 3 + 1];
                    trip[2] = q[(g - 2) * 3 + 2];
                }
            }
        }
        float* o = outp + ((b * Sn + i) * Gn + g) * 3;
        o[0] = (float)trip[0];
        o[1] = (float)trip[1];
        o[2] = (float)trip[2];
    }

    if (t < Sn) {
        const int i = t;
        float sc = 0.f;
        if (i < total) {
            int lo = 0, hi = Sn - 1;
            while (lo < hi) {
                const int mid = (lo + hi) >> 1;
                if (pref[mid + 1] <= i) lo = mid + 1; else hi = mid;
            }
            const int s = lo, j = i - pref[s];
            const int* w = ws + OFF_RES + (b * Sn + s) * WS_STRIDE;
            const float stt = ss[b * Sn + s];
            if (j < nf_s[s]) sc = stt * fsc[w[2 + j]];
            else             sc = stt * rsc[w[66 + (j - nf_s[s])]];
        }
        outp[Bn * Sn * Gn * 3 + b * Sn + t] = sc;
    }
}

extern "C" void kernel_launch(void* const* d_in, const int* in_sizes, int n_in,
                              void* d_out, int out_size, void* d_ws, size_t ws_size,
                              hipStream_t stream) {
    const int*   goals  = (const int*)  d_in[0];
    const float* ss     = (const float*)d_in[1];
    const int*   facts  = (const int*)  d_in[2];
    const float* fsc    = (const float*)d_in[3];
    const int*   heads  = (const int*)  d_in[4];
    const int*   bodies = (const int*)  d_in[5];
    const int*   rlens  = (const int*)  d_in[6];
    const float* rsc    = (const float*)d_in[7];
    int*   ws   = (int*)d_ws;
    float* outp = (float*)d_out;

    hist_kernel   <<<NBLK,   256, 0, stream>>>(facts, ws);
    scan_kernel   <<<1,      256, 0, stream>>>(ws);
    scatter_kernel<<<NBLK,   256, 0, stream>>>(facts, ws);
    match_kernel  <<<Bn * Sn,256, 0, stream>>>(goals, heads, ws);
    select_kernel <<<Bn,     256, 0, stream>>>(goals, ss, facts, fsc, heads, bodies,
                                               rlens, rsc, ws, outp);
}